// Round 10
// baseline (260.035 us; speedup 1.0000x reference)
//
#include <hip/hip_runtime.h>
#include <stdint.h>

typedef short bf16x8 __attribute__((ext_vector_type(8)));
typedef float f32x4 __attribute__((ext_vector_type(4)));

#define D_MODEL 1024
#define NHEAD   16
#define HDIM    64
#define BATCH   4
#define SEQ     2048
#define NTOK    (BATCH * SEQ)   // 8192

#define BM 128
#define BN 128
#define BK 64

#define LOG2E 1.44269504088896340736f

// fp32 -> bf16, round-nearest (ties up): 1 add + shift. Error <= 1/2 ulp.
__device__ __forceinline__ unsigned short f2bf_fast(float f) {
  return (unsigned short)((__float_as_uint(f) + 0x8000u) >> 16);
}

// packed 2x f32 -> bf16 (RNE), lo in bits[15:0], hi in bits[31:16]
__device__ __forceinline__ unsigned int cvt_pk_bf16(float lo, float hi) {
  unsigned int r;
  asm("v_cvt_pk_bf16_f32 %0, %1, %2" : "=v"(r) : "v"(lo), "v"(hi));
  return r;
}

// async global->LDS, 16B per lane; lds ptr wave-uniform (data lands at base + lane*16)
__device__ __forceinline__ void gload_lds16(const unsigned short* g, unsigned short* l) {
  __builtin_amdgcn_global_load_lds((const __attribute__((address_space(1))) void*)g,
                                   (__attribute__((address_space(3))) void*)l,
                                   16, 0, 0);
}

// One launch converts x + 4 weights (dst regions are contiguous in ws).
__global__ __launch_bounds__(256) void cvt_all(
    const float* __restrict__ x, const float* __restrict__ wq,
    const float* __restrict__ wk, const float* __restrict__ wv,
    const float* __restrict__ wo, unsigned short* __restrict__ dst) {
  long i = ((long)blockIdx.x * 256 + threadIdx.x) * 4;
  const float* src; long off;
  if (i < 8388608)       { src = x;  off = 0; }
  else if (i < 9437184)  { src = wq; off = 8388608; }
  else if (i < 10485760) { src = wk; off = 9437184; }
  else if (i < 11534336) { src = wv; off = 10485760; }
  else                   { src = wo; off = 11534336; }
  const float4 v = *(const float4*)(src + (i - off));
  ushort4 o = make_ushort4(f2bf_fast(v.x), f2bf_fast(v.y), f2bf_fast(v.z), f2bf_fast(v.w));
  *(ushort4*)(dst + i) = o;
}

// C = A @ B^T main loop. 128x128 tile, 4 waves 2x2, each wave 64x64 = 4x4 MFMA 16x16x32.
// LDS 16B-chunk index XOR-swizzled by row&7.
// R17: SWAP template — SWAP=1 computes mfma(bfv, af, ·), transposing the D
// fragment so each lane holds 4 CONSECUTIVE B-rows (features) at one A-row
// (token): acc[mt][nt][r] = D[feature 64wx+16nt+4quad+r][token 64wy+16mt+ln15].
// Enables packed b64 epilogue writes for token-major outputs (Q/K, oproj).
template <bool SWAP>
__device__ __forceinline__ void gemm_bt_mainloop(
    const unsigned short* __restrict__ Abase,
    const unsigned short* __restrict__ Bbase,
    int lda, int ldb, int K,
    unsigned short* sA, unsigned short* sB,
    f32x4 acc[4][4]) {
  const int tid = threadIdx.x;
  const int wave = tid >> 6, lane = tid & 63;
  const int ln15 = lane & 15, quad = lane >> 4;
  const int wy = wave >> 1, wx = wave & 1;

#pragma unroll
  for (int mt = 0; mt < 4; ++mt)
#pragma unroll
    for (int nt = 0; nt < 4; ++nt)
      acc[mt][nt] = (f32x4){0.f, 0.f, 0.f, 0.f};

  for (int k0 = 0; k0 < K; k0 += BK) {
    __syncthreads();
#pragma unroll
    for (int i = 0; i < 4; ++i) {
      int chunk = i * 256 + wave * 64 + lane;
      int row = chunk >> 3, c = (chunk & 7) ^ (row & 7);
      gload_lds16(Abase + row * lda + k0 + c * 8, sA + (i * 256 + wave * 64) * 8);
      gload_lds16(Bbase + row * ldb + k0 + c * 8, sB + (i * 256 + wave * 64) * 8);
    }
    __syncthreads();
#pragma unroll
    for (int ks = 0; ks < 2; ++ks) {
      const int swz = ((ks * 4 + quad) ^ (ln15 & 7)) * 8;
      bf16x8 af[4], bfv[4];
#pragma unroll
      for (int t = 0; t < 4; ++t)
        af[t] = *(const bf16x8*)(sA + (64 * wy + 16 * t + ln15) * BK + swz);
#pragma unroll
      for (int t = 0; t < 4; ++t)
        bfv[t] = *(const bf16x8*)(sB + (64 * wx + 16 * t + ln15) * BK + swz);
#pragma unroll
      for (int mt = 0; mt < 4; ++mt)
#pragma unroll
        for (int nt = 0; nt < 4; ++nt) {
          if constexpr (SWAP)
            acc[mt][nt] = __builtin_amdgcn_mfma_f32_16x16x32_bf16(bfv[nt], af[mt], acc[mt][nt], 0, 0, 0);
          else
            acc[mt][nt] = __builtin_amdgcn_mfma_f32_16x16x32_bf16(af[mt], bfv[nt], acc[mt][nt], 0, 0, 0);
        }
    }
  }
}

#define TSTR 136

// Q/K projection (z = 0/1): out = x @ W^T + b, token-major [bh][s][d] output.
// R17: SWAP=1 mainloop -> lane holds 4 consecutive features at one token ->
// sT write is ONE uint2 (2x cvt_pk) per (mt,nt): 16 b64 writes vs 64 b16.
// Bias loads become float4. Read/store phase identical to verified R2 code.
__global__ __launch_bounds__(256) void qkv_qk_gemm(
    const unsigned short* __restrict__ xb,
    const unsigned short* __restrict__ wall,
    const float* __restrict__ bq, const float* __restrict__ bk,
    unsigned short* __restrict__ Qb, unsigned short* __restrict__ Kb) {
  const int n0g = blockIdx.y * BN;        // 0..2047
  const int z = n0g >> 10;                // 0 = Q, 1 = K
  const int n0 = n0g & 1023;
  const float* bias = (z == 0) ? bq : bk;
  const float scale = (z == 0) ? 0.125f * LOG2E : 1.0f;
  unsigned short* dst = (z == 0) ? Qb : Kb;
  const int m0 = blockIdx.x * BM;

  __shared__ __align__(16) unsigned char smem[BM * TSTR * 2];  // 34816 B
  unsigned short* sA = (unsigned short*)smem;
  unsigned short* sB = (unsigned short*)(smem + BM * BK * 2);
  unsigned short* sT = (unsigned short*)smem;

  f32x4 acc[4][4];
  gemm_bt_mainloop<true>(xb + (size_t)m0 * D_MODEL, wall + (size_t)n0g * D_MODEL,
                         D_MODEL, D_MODEL, D_MODEL, sA, sB, acc);

  const int tid = threadIdx.x;
  const int lane = tid & 63, wave = tid >> 6;
  const int ln15 = lane & 15, quad = lane >> 4;
  const int wy = wave >> 1, wx = wave & 1;
  const int b = m0 >> 11;

  __syncthreads();
  // packed token-major transpose: sT[tok][f0..f0+3] one b64 per (mt,nt)
#pragma unroll
  for (int nt = 0; nt < 4; ++nt) {
    const float4 b4 = *(const float4*)(bias + n0 + 64 * wx + 16 * nt + 4 * quad);
#pragma unroll
    for (int mt = 0; mt < 4; ++mt) {
      int tok = 64 * wy + 16 * mt + ln15;
      uint2 pk;
      pk.x = cvt_pk_bf16((acc[mt][nt][0] + b4.x) * scale, (acc[mt][nt][1] + b4.y) * scale);
      pk.y = cvt_pk_bf16((acc[mt][nt][2] + b4.z) * scale, (acc[mt][nt][3] + b4.w) * scale);
      *(uint2*)(sT + tok * TSTR + 64 * wx + 16 * nt + 4 * quad) = pk;
    }
  }
  __syncthreads();
  const int srow = m0 & 2047;
#pragma unroll
  for (int i = 0; i < 8; ++i) {
    int tok = (tid >> 4) + i * 16;
    int jj = (tid & 15) * 8;
    bf16x8 val = *(const bf16x8*)(sT + tok * TSTR + jj);
    int feature = n0 + jj;
    int h = feature >> 6, d = feature & 63;
    *(bf16x8*)(dst + (((size_t)(b * NHEAD + h)) * SEQ + srow + tok) * HDIM + d) = val;
  }
}

// V projection (z = 2): feature-major transposed output Vt[bh][d][s].
// Keeps SWAP=0 (old operand order) + the twice-verified feature-major epilogue.
__global__ __launch_bounds__(256) void qkv_v_gemm(
    const unsigned short* __restrict__ xb,
    const unsigned short* __restrict__ wall,
    const float* __restrict__ bv,
    unsigned short* __restrict__ Vt) {
  const int n0g = 2048 + blockIdx.y * BN;  // 2048..3071
  const int n0 = n0g & 1023;
  const int m0 = blockIdx.x * BM;

  __shared__ __align__(16) unsigned char smem[BM * TSTR * 2];  // 34816 B
  unsigned short* sA = (unsigned short*)smem;
  unsigned short* sB = (unsigned short*)(smem + BM * BK * 2);
  unsigned short* sT = (unsigned short*)smem;

  f32x4 acc[4][4];
  gemm_bt_mainloop<false>(xb + (size_t)m0 * D_MODEL, wall + (size_t)n0g * D_MODEL,
                          D_MODEL, D_MODEL, D_MODEL, sA, sB, acc);

  const int tid = threadIdx.x;
  const int lane = tid & 63, wave = tid >> 6;
  const int ln15 = lane & 15, quad = lane >> 4;
  const int wy = wave >> 1, wx = wave & 1;
  const int b = m0 >> 11;

  __syncthreads();
#pragma unroll
  for (int mt = 0; mt < 4; ++mt)
#pragma unroll
    for (int nt = 0; nt < 4; ++nt) {
      int j = 64 * wx + 16 * nt + ln15;
      float bj = bv[n0 + j];
#pragma unroll
      for (int r = 0; r < 4; r += 2) {
        int tok = 64 * wy + 16 * mt + quad * 4 + r;
        unsigned int pk = (unsigned int)f2bf_fast(acc[mt][nt][r] + bj) |
                          ((unsigned int)f2bf_fast(acc[mt][nt][r + 1] + bj) << 16);
        *(unsigned int*)(sT + j * TSTR + tok) = pk;
      }
    }
  __syncthreads();
  const int sbase = (m0 & 2047) + (tid & 15) * 8;
#pragma unroll
  for (int i = 0; i < 8; ++i) {
    int j = (tid >> 4) + i * 16;
    int feature = n0 + j;
    int h = feature >> 6, d = feature & 63;
    bf16x8 val = *(const bf16x8*)(sT + j * TSTR + (tid & 15) * 8);
    *(bf16x8*)(Vt + (((size_t)(b * NHEAD + h)) * HDIM + d) * SEQ + sbase) = val;
  }
}

// Flash attention — R16 VERBATIM (verified pass, 80.8us, MfmaUtil 40).
// 3-barrier fused QK+softmax; PSTR=72 sP (PSTR=64 XOR swizzle BANNED per R15);
// kappa-permuted K; ones-MFMA lsum; cvt_pk packing; XCD swizzle; setprio.
#define PSTR 72
__global__ __launch_bounds__(256, 4) void attn_kernel(
    const unsigned short* __restrict__ Qb,
    const unsigned short* __restrict__ Kb,
    const unsigned short* __restrict__ Vt,
    unsigned short* __restrict__ ctxb) {
  // XCD-aware bijective swizzle (1024 blocks % 8 XCDs == 0)
  const int flat = blockIdx.y * gridDim.x + blockIdx.x;   // dispatch-linear id
  const int sbid = (flat & 7) * 128 + (flat >> 3);
  const int qb = sbid & 15;
  const int bh = sbid >> 4;
  const int s0 = qb * 128;
  const int tid = threadIdx.x, wave = tid >> 6, lane = tid & 63;
  const int ln15 = lane & 15, quad = lane >> 4;

  __shared__ __align__(16) unsigned short sK[64 * 64], sV[64 * 64], sP[128 * PSTR];

  const unsigned short* Qg = Qb + (size_t)bh * SEQ * HDIM;
  const unsigned short* Kg = Kb + (size_t)bh * SEQ * HDIM;
  const unsigned short* Vg = Vt + (size_t)bh * HDIM * SEQ;

  // Q fragments in registers
  bf16x8 qf[2][2];
#pragma unroll
  for (int mt = 0; mt < 2; ++mt)
#pragma unroll
    for (int ks = 0; ks < 2; ++ks)
      qf[mt][ks] = *(const bf16x8*)(Qg + (s0 + 32 * wave + 16 * mt + ln15) * HDIM + ks * 32 + quad * 8);

  // hoisted staging addresses; K rows staged PERMUTED: lds row i <- global key kappa(i)
  const int chunk0 = wave * 64 + lane;
  const int row0 = chunk0 >> 3, c0 = (chunk0 & 7) ^ (row0 & 7);
  const int chunk1 = 256 + wave * 64 + lane;
  const int row1 = chunk1 >> 3, c1 = (chunk1 & 7) ^ (row1 & 7);
  const int krow0 = ((row0 & 15) << 2) | (row0 >> 4);  // kappa
  const int krow1 = ((row1 & 15) << 2) | (row1 >> 4);
  const unsigned short* Kp0 = Kg + krow0 * HDIM + c0 * 8;
  const unsigned short* Kp1 = Kg + krow1 * HDIM + c1 * 8;
  const unsigned short* Vp0 = Vg + row0 * SEQ + c0 * 8;
  const unsigned short* Vp1 = Vg + row1 * SEQ + c1 * 8;
  unsigned short* dK0 = sK + chunk0 * 8;
  unsigned short* dK1 = sK + chunk1 * 8;
  unsigned short* dV0 = sV + chunk0 * 8;
  unsigned short* dV1 = sV + chunk1 * 8;

  // b64 P-write base: row (32w+4q), col ln15*4 (8B-aligned) — verified PSTR=72 layout
  unsigned short* sPw = sP + (32 * wave + 4 * quad) * PSTR + ln15 * 4;

  const f32x4 zero4 = (f32x4){0.f, 0.f, 0.f, 0.f};

  // all-ones bf16 B fragment for row-sum MFMAs
  bf16x8 ones8;
#pragma unroll
  for (int j = 0; j < 8; ++j) ones8[j] = (short)0x3F80;

  f32x4 lsum[2];
  f32x4 O[2][4];
#pragma unroll
  for (int mt = 0; mt < 2; ++mt) {
    lsum[mt] = (f32x4){0.f, 0.f, 0.f, 0.f};
#pragma unroll
    for (int dt = 0; dt < 4; ++dt) O[mt][dt] = (f32x4){0.f, 0.f, 0.f, 0.f};
  }

  // prologue: issue K(0) then V(0) (4 loads in flight entering the loop)
  gload_lds16(Kp0, dK0);
  gload_lds16(Kp1, dK1);
  __builtin_amdgcn_sched_barrier(0);
  gload_lds16(Vp0, dV0);
  gload_lds16(Vp1, dV1);
  __builtin_amdgcn_sched_barrier(0);

  for (int t = 0; t < 32; ++t) {
    const int k0 = t << 6;

    // ---- barrier A: retire K(t) pair (oldest); V(t) stays in flight ----
    asm volatile("s_waitcnt vmcnt(2)" ::: "memory");
    __builtin_amdgcn_s_barrier();                      // K(t) visible to all waves

    // ---- barrier-free region: QK(t) MFMA + softmax(t) VALU (cross-wave mix) ----
    f32x4 sc[2][4];
    __builtin_amdgcn_s_setprio(1);
    {
      const int swk = (quad ^ (ln15 & 7)) * 8;
#pragma unroll
      for (int nt = 0; nt < 4; ++nt) {
        bf16x8 bk8 = *(const bf16x8*)(sK + (16 * nt + ln15) * 64 + swk);
#pragma unroll
        for (int mt = 0; mt < 2; ++mt)
          sc[mt][nt] = __builtin_amdgcn_mfma_f32_16x16x32_bf16(qf[mt][0], bk8, zero4, 0, 0, 0);
      }
    }
    {
      const int swk = ((4 + quad) ^ (ln15 & 7)) * 8;
#pragma unroll
      for (int nt = 0; nt < 4; ++nt) {
        bf16x8 bk8 = *(const bf16x8*)(sK + (16 * nt + ln15) * 64 + swk);
#pragma unroll
        for (int mt = 0; mt < 2; ++mt)
          sc[mt][nt] = __builtin_amdgcn_mfma_f32_16x16x32_bf16(qf[mt][1], bk8, sc[mt][nt], 0, 0, 0);
      }
    }
    __builtin_amdgcn_s_setprio(0);

    // p = exp2(s); pack pairs via v_cvt_pk_bf16_f32; ONE ds_write_b64 per (mt,r)
#pragma unroll
    for (int mt = 0; mt < 2; ++mt)
#pragma unroll
      for (int r = 0; r < 4; ++r) {
        float p0 = __builtin_amdgcn_exp2f(sc[mt][0][r]);
        float p1 = __builtin_amdgcn_exp2f(sc[mt][1][r]);
        float p2 = __builtin_amdgcn_exp2f(sc[mt][2][r]);
        float p3 = __builtin_amdgcn_exp2f(sc[mt][3][r]);
        uint2 pk;
        pk.x = cvt_pk_bf16(p0, p1);
        pk.y = cvt_pk_bf16(p2, p3);
        *(uint2*)(sPw + (16 * mt + r) * PSTR) = pk;
      }
    // sP rows [32w,32w+32) wave-private; same-wave LDS in-order -> no barrier

    // ---- barrier B: drain V(t) (only thing outstanding); also proves all
    //      waves finished reading sK in QK(t) ----
    __builtin_amdgcn_sched_barrier(0);
    asm volatile("s_waitcnt vmcnt(0)" ::: "memory");
    __builtin_amdgcn_s_barrier();                      // V(t) visible to all waves
    if (t < 31) {                                      // K(t+1) -> sK (safe now)
      gload_lds16(Kp0 + (k0 + 64) * HDIM, dK0);
      gload_lds16(Kp1 + (k0 + 64) * HDIM, dK1);
    }
    __builtin_amdgcn_sched_barrier(0);                 // pin K-issue before PV

    // O += P V  (sP columns key-ordered to match sV); l row-sums via ones-MFMA
    __builtin_amdgcn_s_setprio(1);
#pragma unroll
    for (int ks = 0; ks < 2; ++ks) {
      const int swv = ((ks * 4 + quad) ^ (ln15 & 7)) * 8;
      bf16x8 ap[2];
#pragma unroll
      for (int mt = 0; mt < 2; ++mt)
        ap[mt] = *(const bf16x8*)(sP + (32 * wave + 16 * mt + ln15) * PSTR + ks * 32 + quad * 8);
#pragma unroll
      for (int mt = 0; mt < 2; ++mt)
        lsum[mt] = __builtin_amdgcn_mfma_f32_16x16x32_bf16(ap[mt], ones8, lsum[mt], 0, 0, 0);
#pragma unroll
      for (int dt = 0; dt < 4; ++dt) {
        bf16x8 bv8 = *(const bf16x8*)(sV + (16 * dt + ln15) * 64 + swv);
#pragma unroll
        for (int mt = 0; mt < 2; ++mt)
          O[mt][dt] = __builtin_amdgcn_mfma_f32_16x16x32_bf16(ap[mt], bv8, O[mt][dt], 0, 0, 0);
      }
    }
    __builtin_amdgcn_s_setprio(0);

    // ---- barrier C: all waves past sV reads -> safe to overwrite sV ----
    __builtin_amdgcn_sched_barrier(0);
    __builtin_amdgcn_s_barrier();
    if (t < 31) {                                      // V(t+1) -> sV
      gload_lds16(Vp0 + k0 + 64, dV0);
      gload_lds16(Vp1 + k0 + 64, dV1);
    }
    __builtin_amdgcn_sched_barrier(0);                 // pin V-issue at loop end
  }
  asm volatile("s_waitcnt vmcnt(0)" ::: "memory");     // nothing outstanding; safety

  // epilogue: lsum[mt][r] already holds the full row sum (every column equal)
  const int b = bh >> 4, h = bh & 15;
#pragma unroll
  for (int mt = 0; mt < 2; ++mt)
#pragma unroll
    for (int r = 0; r < 4; ++r) {
      float inv = 1.0f / lsum[mt][r];
      int token = b * SEQ + s0 + 32 * wave + 16 * mt + quad * 4 + r;
#pragma unroll
      for (int dt = 0; dt < 4; ++dt)
        ctxb[(size_t)token * D_MODEL + h * HDIM + 16 * dt + ln15] = f2bf_fast(O[mt][dt][r] * inv);
    }
}

// out = ctx @ wo^T + bo  (fp32 output).
// R17: SWAP=1 mainloop -> lane holds 4 consecutive output features at one
// token -> float4 bias load + ONE global_store_dwordx4 per (mt,nt)
// (16 stores vs 64; same 64B-segment coalescing).
__global__ __launch_bounds__(256) void oproj_kernel(
    const unsigned short* __restrict__ ctxb,
    const unsigned short* __restrict__ wob,
    const float* __restrict__ bo,
    float* __restrict__ out) {
  const int m0 = blockIdx.x * BM, n0 = blockIdx.y * BN;
  __shared__ __align__(16) unsigned short sA[BM * BK], sB[BN * BK];
  f32x4 acc[4][4];
  gemm_bt_mainloop<true>(ctxb + (size_t)m0 * D_MODEL, wob + (size_t)n0 * D_MODEL,
                         D_MODEL, D_MODEL, D_MODEL, sA, sB, acc);

  const int lane = threadIdx.x & 63, wave = threadIdx.x >> 6;
  const int ln15 = lane & 15, quad = lane >> 4;
  const int wy = wave >> 1, wx = wave & 1;
#pragma unroll
  for (int nt = 0; nt < 4; ++nt) {
    const int j0 = n0 + 64 * wx + 16 * nt + 4 * quad;
    const float4 b4 = *(const float4*)(bo + j0);
#pragma unroll
    for (int mt = 0; mt < 4; ++mt) {
      int n = m0 + 64 * wy + 16 * mt + ln15;
      float4 o;
      o.x = acc[mt][nt][0] + b4.x;
      o.y = acc[mt][nt][1] + b4.y;
      o.z = acc[mt][nt][2] + b4.z;
      o.w = acc[mt][nt][3] + b4.w;
      *(float4*)(out + (size_t)n * D_MODEL + j0) = o;
    }
  }
}

extern "C" void kernel_launch(void* const* d_in, const int* in_sizes, int n_in,
                              void* d_out, int out_size, void* d_ws, size_t ws_size,
                              hipStream_t stream) {
  const float* x  = (const float*)d_in[0];
  const float* wq = (const float*)d_in[1];
  const float* bq = (const float*)d_in[2];
  const float* wk = (const float*)d_in[3];
  const float* bk = (const float*)d_in[4];
  const float* wv = (const float*)d_in[5];
  const float* bv = (const float*)d_in[6];
  const float* wo = (const float*)d_in[7];
  const float* bo = (const float*)d_in[8];
  float* out = (float*)d_out;

  // workspace layout (bf16 elements); xb..wob contiguous for cvt_all;
  // wq|wk|wv contiguous -> stacked [3072,1024] for merged qkv staging
  unsigned short* ws   = (unsigned short*)d_ws;
  unsigned short* xb   = ws;              // 8388608
  unsigned short* wall = ws + 8388608;    // [3072][1024] = wq|wk|wv
  unsigned short* wob  = ws + 11534336;
  unsigned short* Qb   = ws + 12582912;   // [B,H,S,Dh]
  unsigned short* Kb   = ws + 20971520;   // [B,H,S,Dh]
  unsigned short* Vtb  = ws + 29360128;   // [B,H,Dh,S]
  unsigned short* ctxb = ws + 37748736;   // [N, D]

  cvt_all<<<12288, 256, 0, stream>>>(x, wq, wk, wv, wo, ws);

  qkv_qk_gemm<<<dim3(64, 16), 256, 0, stream>>>(xb, wall, bq, bk, Qb, Kb);
  qkv_v_gemm<<<dim3(64, 8), 256, 0, stream>>>(xb, wall, bv, Vtb);
  attn_kernel<<<dim3(16, 64), 256, 0, stream>>>(Qb, Kb, Vtb, ctxb);
  oproj_kernel<<<dim3(64, 8), 256, 0, stream>>>(ctxb, wob, bo, out);
}

// Round 11
// 256.216 us; speedup vs baseline: 1.0149x; 1.0149x over previous
//
#include <hip/hip_runtime.h>
#include <stdint.h>

typedef short bf16x8 __attribute__((ext_vector_type(8)));
typedef float f32x4 __attribute__((ext_vector_type(4)));

#define D_MODEL 1024
#define NHEAD   16
#define HDIM    64
#define BATCH   4
#define SEQ     2048
#define NTOK    (BATCH * SEQ)   // 8192

#define BM 128
#define BN 128
#define BK 64

#define LOG2E 1.44269504088896340736f

// fp32 -> bf16, round-nearest (ties up): 1 add + shift. Error <= 1/2 ulp.
__device__ __forceinline__ unsigned short f2bf_fast(float f) {
  return (unsigned short)((__float_as_uint(f) + 0x8000u) >> 16);
}

// packed 2x f32 -> bf16 (RNE), lo in bits[15:0], hi in bits[31:16]
__device__ __forceinline__ unsigned int cvt_pk_bf16(float lo, float hi) {
  unsigned int r;
  asm("v_cvt_pk_bf16_f32 %0, %1, %2" : "=v"(r) : "v"(lo), "v"(hi));
  return r;
}

// async global->LDS, 16B per lane; lds ptr wave-uniform (data lands at base + lane*16)
__device__ __forceinline__ void gload_lds16(const unsigned short* g, unsigned short* l) {
  __builtin_amdgcn_global_load_lds((const __attribute__((address_space(1))) void*)g,
                                   (__attribute__((address_space(3))) void*)l,
                                   16, 0, 0);
}

// One launch converts x + 4 weights (dst regions are contiguous in ws).
__global__ __launch_bounds__(256) void cvt_all(
    const float* __restrict__ x, const float* __restrict__ wq,
    const float* __restrict__ wk, const float* __restrict__ wv,
    const float* __restrict__ wo, unsigned short* __restrict__ dst) {
  long i = ((long)blockIdx.x * 256 + threadIdx.x) * 4;
  const float* src; long off;
  if (i < 8388608)       { src = x;  off = 0; }
  else if (i < 9437184)  { src = wq; off = 8388608; }
  else if (i < 10485760) { src = wk; off = 9437184; }
  else if (i < 11534336) { src = wv; off = 10485760; }
  else                   { src = wo; off = 11534336; }
  const float4 v = *(const float4*)(src + (i - off));
  ushort4 o = make_ushort4(f2bf_fast(v.x), f2bf_fast(v.y), f2bf_fast(v.z), f2bf_fast(v.w));
  *(ushort4*)(dst + i) = o;
}

// C = A @ B^T main loop. 128x128 tile, 4 waves 2x2, each wave 64x64 = 4x4 MFMA 16x16x32.
// LDS 16B-chunk index XOR-swizzled by row&7.
// SWAP=1 computes mfma(bfv, af, ·): D transposed so each lane holds 4 CONSECUTIVE
// B-rows (features) at one A-row (token) -> packed b64 epilogue writes.
template <bool SWAP>
__device__ __forceinline__ void gemm_bt_mainloop(
    const unsigned short* __restrict__ Abase,
    const unsigned short* __restrict__ Bbase,
    int lda, int ldb, int K,
    unsigned short* sA, unsigned short* sB,
    f32x4 acc[4][4]) {
  const int tid = threadIdx.x;
  const int wave = tid >> 6, lane = tid & 63;
  const int ln15 = lane & 15, quad = lane >> 4;
  const int wy = wave >> 1, wx = wave & 1;

#pragma unroll
  for (int mt = 0; mt < 4; ++mt)
#pragma unroll
    for (int nt = 0; nt < 4; ++nt)
      acc[mt][nt] = (f32x4){0.f, 0.f, 0.f, 0.f};

  for (int k0 = 0; k0 < K; k0 += BK) {
    __syncthreads();
#pragma unroll
    for (int i = 0; i < 4; ++i) {
      int chunk = i * 256 + wave * 64 + lane;
      int row = chunk >> 3, c = (chunk & 7) ^ (row & 7);
      gload_lds16(Abase + row * lda + k0 + c * 8, sA + (i * 256 + wave * 64) * 8);
      gload_lds16(Bbase + row * ldb + k0 + c * 8, sB + (i * 256 + wave * 64) * 8);
    }
    __syncthreads();
#pragma unroll
    for (int ks = 0; ks < 2; ++ks) {
      const int swz = ((ks * 4 + quad) ^ (ln15 & 7)) * 8;
      bf16x8 af[4], bfv[4];
#pragma unroll
      for (int t = 0; t < 4; ++t)
        af[t] = *(const bf16x8*)(sA + (64 * wy + 16 * t + ln15) * BK + swz);
#pragma unroll
      for (int t = 0; t < 4; ++t)
        bfv[t] = *(const bf16x8*)(sB + (64 * wx + 16 * t + ln15) * BK + swz);
#pragma unroll
      for (int mt = 0; mt < 4; ++mt)
#pragma unroll
        for (int nt = 0; nt < 4; ++nt) {
          if constexpr (SWAP)
            acc[mt][nt] = __builtin_amdgcn_mfma_f32_16x16x32_bf16(bfv[nt], af[mt], acc[mt][nt], 0, 0, 0);
          else
            acc[mt][nt] = __builtin_amdgcn_mfma_f32_16x16x32_bf16(af[mt], bfv[nt], acc[mt][nt], 0, 0, 0);
        }
    }
  }
}

#define TSTR 136

// Merged QKV projection (R18: single launch again — R17's 2-kernel split cost
// ~+4us of dispatch/tail overhead and the packed epilogue only broke even).
// z = (blockIdx.y*128)>>10 selects Q/K (SWAP=1, packed token-major epilogue,
// verified R17) or V (SWAP=0, feature-major epilogue, verified R2..R16).
__global__ __launch_bounds__(256) void qkv_gemm(
    const unsigned short* __restrict__ xb,
    const unsigned short* __restrict__ wall,
    const float* __restrict__ bq, const float* __restrict__ bk, const float* __restrict__ bv,
    unsigned short* __restrict__ Qb, unsigned short* __restrict__ Kb,
    unsigned short* __restrict__ Vt) {
  const int n0g = blockIdx.y * BN;        // 0..3071
  const int z = n0g >> 10;
  const int n0 = n0g & 1023;
  const int m0 = blockIdx.x * BM;

  __shared__ __align__(16) unsigned char smem[BM * TSTR * 2];  // 34816 B
  unsigned short* sA = (unsigned short*)smem;
  unsigned short* sB = (unsigned short*)(smem + BM * BK * 2);
  unsigned short* sT = (unsigned short*)smem;

  const int tid = threadIdx.x;
  const int lane = tid & 63, wave = tid >> 6;
  const int ln15 = lane & 15, quad = lane >> 4;
  const int wy = wave >> 1, wx = wave & 1;
  const int b = m0 >> 11;

  f32x4 acc[4][4];

  if (z == 2) {
    // ---- V: SWAP=0 mainloop + feature-major transpose epilogue (verified) ----
    gemm_bt_mainloop<false>(xb + (size_t)m0 * D_MODEL, wall + (size_t)n0g * D_MODEL,
                            D_MODEL, D_MODEL, D_MODEL, sA, sB, acc);
    __syncthreads();
#pragma unroll
    for (int mt = 0; mt < 4; ++mt)
#pragma unroll
      for (int nt = 0; nt < 4; ++nt) {
        int j = 64 * wx + 16 * nt + ln15;
        float bj = bv[n0 + j];
#pragma unroll
        for (int r = 0; r < 4; r += 2) {
          int tok = 64 * wy + 16 * mt + quad * 4 + r;
          unsigned int pk = (unsigned int)f2bf_fast(acc[mt][nt][r] + bj) |
                            ((unsigned int)f2bf_fast(acc[mt][nt][r + 1] + bj) << 16);
          *(unsigned int*)(sT + j * TSTR + tok) = pk;
        }
      }
    __syncthreads();
    const int sbase = (m0 & 2047) + (tid & 15) * 8;
#pragma unroll
    for (int i = 0; i < 8; ++i) {
      int j = (tid >> 4) + i * 16;
      int feature = n0 + j;
      int h = feature >> 6, d = feature & 63;
      bf16x8 val = *(const bf16x8*)(sT + j * TSTR + (tid & 15) * 8);
      *(bf16x8*)(Vt + (((size_t)(b * NHEAD + h)) * HDIM + d) * SEQ + sbase) = val;
    }
  } else {
    // ---- Q/K: SWAP=1 mainloop + packed token-major epilogue (verified R17) ----
    const float* bias = (z == 0) ? bq : bk;
    const float scale = (z == 0) ? 0.125f * LOG2E : 1.0f;
    unsigned short* dst = (z == 0) ? Qb : Kb;

    gemm_bt_mainloop<true>(xb + (size_t)m0 * D_MODEL, wall + (size_t)n0g * D_MODEL,
                           D_MODEL, D_MODEL, D_MODEL, sA, sB, acc);
    __syncthreads();
#pragma unroll
    for (int nt = 0; nt < 4; ++nt) {
      const float4 b4 = *(const float4*)(bias + n0 + 64 * wx + 16 * nt + 4 * quad);
#pragma unroll
      for (int mt = 0; mt < 4; ++mt) {
        int tok = 64 * wy + 16 * mt + ln15;
        uint2 pk;
        pk.x = cvt_pk_bf16((acc[mt][nt][0] + b4.x) * scale, (acc[mt][nt][1] + b4.y) * scale);
        pk.y = cvt_pk_bf16((acc[mt][nt][2] + b4.z) * scale, (acc[mt][nt][3] + b4.w) * scale);
        *(uint2*)(sT + tok * TSTR + 64 * wx + 16 * nt + 4 * quad) = pk;
      }
    }
    __syncthreads();
    const int srow = m0 & 2047;
#pragma unroll
    for (int i = 0; i < 8; ++i) {
      int tok = (tid >> 4) + i * 16;
      int jj = (tid & 15) * 8;
      bf16x8 val = *(const bf16x8*)(sT + tok * TSTR + jj);
      int feature = n0 + jj;
      int h = feature >> 6, d = feature & 63;
      *(bf16x8*)(dst + (((size_t)(b * NHEAD + h)) * SEQ + srow + tok) * HDIM + d) = val;
    }
  }
}

// Flash attention — R16 VERBATIM (verified pass x2: 80.8us and 79.0us).
// 3-barrier fused QK+softmax; PSTR=72 sP (PSTR=64 XOR swizzle BANNED per R15);
// kappa-permuted K; ones-MFMA lsum; cvt_pk packing; XCD swizzle; setprio.
#define PSTR 72
__global__ __launch_bounds__(256, 4) void attn_kernel(
    const unsigned short* __restrict__ Qb,
    const unsigned short* __restrict__ Kb,
    const unsigned short* __restrict__ Vt,
    unsigned short* __restrict__ ctxb) {
  // XCD-aware bijective swizzle (1024 blocks % 8 XCDs == 0)
  const int flat = blockIdx.y * gridDim.x + blockIdx.x;   // dispatch-linear id
  const int sbid = (flat & 7) * 128 + (flat >> 3);
  const int qb = sbid & 15;
  const int bh = sbid >> 4;
  const int s0 = qb * 128;
  const int tid = threadIdx.x, wave = tid >> 6, lane = tid & 63;
  const int ln15 = lane & 15, quad = lane >> 4;

  __shared__ __align__(16) unsigned short sK[64 * 64], sV[64 * 64], sP[128 * PSTR];

  const unsigned short* Qg = Qb + (size_t)bh * SEQ * HDIM;
  const unsigned short* Kg = Kb + (size_t)bh * SEQ * HDIM;
  const unsigned short* Vg = Vt + (size_t)bh * HDIM * SEQ;

  // Q fragments in registers
  bf16x8 qf[2][2];
#pragma unroll
  for (int mt = 0; mt < 2; ++mt)
#pragma unroll
    for (int ks = 0; ks < 2; ++ks)
      qf[mt][ks] = *(const bf16x8*)(Qg + (s0 + 32 * wave + 16 * mt + ln15) * HDIM + ks * 32 + quad * 8);

  // hoisted staging addresses; K rows staged PERMUTED: lds row i <- global key kappa(i)
  const int chunk0 = wave * 64 + lane;
  const int row0 = chunk0 >> 3, c0 = (chunk0 & 7) ^ (row0 & 7);
  const int chunk1 = 256 + wave * 64 + lane;
  const int row1 = chunk1 >> 3, c1 = (chunk1 & 7) ^ (row1 & 7);
  const int krow0 = ((row0 & 15) << 2) | (row0 >> 4);  // kappa
  const int krow1 = ((row1 & 15) << 2) | (row1 >> 4);
  const unsigned short* Kp0 = Kg + krow0 * HDIM + c0 * 8;
  const unsigned short* Kp1 = Kg + krow1 * HDIM + c1 * 8;
  const unsigned short* Vp0 = Vg + row0 * SEQ + c0 * 8;
  const unsigned short* Vp1 = Vg + row1 * SEQ + c1 * 8;
  unsigned short* dK0 = sK + chunk0 * 8;
  unsigned short* dK1 = sK + chunk1 * 8;
  unsigned short* dV0 = sV + chunk0 * 8;
  unsigned short* dV1 = sV + chunk1 * 8;

  // b64 P-write base: row (32w+4q), col ln15*4 (8B-aligned) — verified PSTR=72 layout
  unsigned short* sPw = sP + (32 * wave + 4 * quad) * PSTR + ln15 * 4;

  const f32x4 zero4 = (f32x4){0.f, 0.f, 0.f, 0.f};

  // all-ones bf16 B fragment for row-sum MFMAs
  bf16x8 ones8;
#pragma unroll
  for (int j = 0; j < 8; ++j) ones8[j] = (short)0x3F80;

  f32x4 lsum[2];
  f32x4 O[2][4];
#pragma unroll
  for (int mt = 0; mt < 2; ++mt) {
    lsum[mt] = (f32x4){0.f, 0.f, 0.f, 0.f};
#pragma unroll
    for (int dt = 0; dt < 4; ++dt) O[mt][dt] = (f32x4){0.f, 0.f, 0.f, 0.f};
  }

  // prologue: issue K(0) then V(0) (4 loads in flight entering the loop)
  gload_lds16(Kp0, dK0);
  gload_lds16(Kp1, dK1);
  __builtin_amdgcn_sched_barrier(0);
  gload_lds16(Vp0, dV0);
  gload_lds16(Vp1, dV1);
  __builtin_amdgcn_sched_barrier(0);

  for (int t = 0; t < 32; ++t) {
    const int k0 = t << 6;

    // ---- barrier A: retire K(t) pair (oldest); V(t) stays in flight ----
    asm volatile("s_waitcnt vmcnt(2)" ::: "memory");
    __builtin_amdgcn_s_barrier();                      // K(t) visible to all waves

    // ---- barrier-free region: QK(t) MFMA + softmax(t) VALU (cross-wave mix) ----
    f32x4 sc[2][4];
    __builtin_amdgcn_s_setprio(1);
    {
      const int swk = (quad ^ (ln15 & 7)) * 8;
#pragma unroll
      for (int nt = 0; nt < 4; ++nt) {
        bf16x8 bk8 = *(const bf16x8*)(sK + (16 * nt + ln15) * 64 + swk);
#pragma unroll
        for (int mt = 0; mt < 2; ++mt)
          sc[mt][nt] = __builtin_amdgcn_mfma_f32_16x16x32_bf16(qf[mt][0], bk8, zero4, 0, 0, 0);
      }
    }
    {
      const int swk = ((4 + quad) ^ (ln15 & 7)) * 8;
#pragma unroll
      for (int nt = 0; nt < 4; ++nt) {
        bf16x8 bk8 = *(const bf16x8*)(sK + (16 * nt + ln15) * 64 + swk);
#pragma unroll
        for (int mt = 0; mt < 2; ++mt)
          sc[mt][nt] = __builtin_amdgcn_mfma_f32_16x16x32_bf16(qf[mt][1], bk8, sc[mt][nt], 0, 0, 0);
      }
    }
    __builtin_amdgcn_s_setprio(0);

    // p = exp2(s); pack pairs via v_cvt_pk_bf16_f32; ONE ds_write_b64 per (mt,r)
#pragma unroll
    for (int mt = 0; mt < 2; ++mt)
#pragma unroll
      for (int r = 0; r < 4; ++r) {
        float p0 = __builtin_amdgcn_exp2f(sc[mt][0][r]);
        float p1 = __builtin_amdgcn_exp2f(sc[mt][1][r]);
        float p2 = __builtin_amdgcn_exp2f(sc[mt][2][r]);
        float p3 = __builtin_amdgcn_exp2f(sc[mt][3][r]);
        uint2 pk;
        pk.x = cvt_pk_bf16(p0, p1);
        pk.y = cvt_pk_bf16(p2, p3);
        *(uint2*)(sPw + (16 * mt + r) * PSTR) = pk;
      }
    // sP rows [32w,32w+32) wave-private; same-wave LDS in-order -> no barrier

    // ---- barrier B: drain V(t) (only thing outstanding); also proves all
    //      waves finished reading sK in QK(t) ----
    __builtin_amdgcn_sched_barrier(0);
    asm volatile("s_waitcnt vmcnt(0)" ::: "memory");
    __builtin_amdgcn_s_barrier();                      // V(t) visible to all waves
    if (t < 31) {                                      // K(t+1) -> sK (safe now)
      gload_lds16(Kp0 + (k0 + 64) * HDIM, dK0);
      gload_lds16(Kp1 + (k0 + 64) * HDIM, dK1);
    }
    __builtin_amdgcn_sched_barrier(0);                 // pin K-issue before PV

    // O += P V  (sP columns key-ordered to match sV); l row-sums via ones-MFMA
    __builtin_amdgcn_s_setprio(1);
#pragma unroll
    for (int ks = 0; ks < 2; ++ks) {
      const int swv = ((ks * 4 + quad) ^ (ln15 & 7)) * 8;
      bf16x8 ap[2];
#pragma unroll
      for (int mt = 0; mt < 2; ++mt)
        ap[mt] = *(const bf16x8*)(sP + (32 * wave + 16 * mt + ln15) * PSTR + ks * 32 + quad * 8);
#pragma unroll
      for (int mt = 0; mt < 2; ++mt)
        lsum[mt] = __builtin_amdgcn_mfma_f32_16x16x32_bf16(ap[mt], ones8, lsum[mt], 0, 0, 0);
#pragma unroll
      for (int dt = 0; dt < 4; ++dt) {
        bf16x8 bv8 = *(const bf16x8*)(sV + (16 * dt + ln15) * 64 + swv);
#pragma unroll
        for (int mt = 0; mt < 2; ++mt)
          O[mt][dt] = __builtin_amdgcn_mfma_f32_16x16x32_bf16(ap[mt], bv8, O[mt][dt], 0, 0, 0);
      }
    }
    __builtin_amdgcn_s_setprio(0);

    // ---- barrier C: all waves past sV reads -> safe to overwrite sV ----
    __builtin_amdgcn_sched_barrier(0);
    __builtin_amdgcn_s_barrier();
    if (t < 31) {                                      // V(t+1) -> sV
      gload_lds16(Vp0 + k0 + 64, dV0);
      gload_lds16(Vp1 + k0 + 64, dV1);
    }
    __builtin_amdgcn_sched_barrier(0);                 // pin V-issue at loop end
  }
  asm volatile("s_waitcnt vmcnt(0)" ::: "memory");     // nothing outstanding; safety

  // epilogue: lsum[mt][r] already holds the full row sum (every column equal)
  const int b = bh >> 4, h = bh & 15;
#pragma unroll
  for (int mt = 0; mt < 2; ++mt)
#pragma unroll
    for (int r = 0; r < 4; ++r) {
      float inv = 1.0f / lsum[mt][r];
      int token = b * SEQ + s0 + 32 * wave + 16 * mt + quad * 4 + r;
#pragma unroll
      for (int dt = 0; dt < 4; ++dt)
        ctxb[(size_t)token * D_MODEL + h * HDIM + 16 * dt + ln15] = f2bf_fast(O[mt][dt][r] * inv);
    }
}

// out = ctx @ wo^T + bo  (fp32 output). SWAP=1 -> float4 bias + one
// global_store_dwordx4 per (mt,nt) (verified R17).
__global__ __launch_bounds__(256) void oproj_kernel(
    const unsigned short* __restrict__ ctxb,
    const unsigned short* __restrict__ wob,
    const float* __restrict__ bo,
    float* __restrict__ out) {
  const int m0 = blockIdx.x * BM, n0 = blockIdx.y * BN;
  __shared__ __align__(16) unsigned short sA[BM * BK], sB[BN * BK];
  f32x4 acc[4][4];
  gemm_bt_mainloop<true>(ctxb + (size_t)m0 * D_MODEL, wob + (size_t)n0 * D_MODEL,
                         D_MODEL, D_MODEL, D_MODEL, sA, sB, acc);

  const int lane = threadIdx.x & 63, wave = threadIdx.x >> 6;
  const int ln15 = lane & 15, quad = lane >> 4;
  const int wy = wave >> 1, wx = wave & 1;
#pragma unroll
  for (int nt = 0; nt < 4; ++nt) {
    const int j0 = n0 + 64 * wx + 16 * nt + 4 * quad;
    const float4 b4 = *(const float4*)(bo + j0);
#pragma unroll
    for (int mt = 0; mt < 4; ++mt) {
      int n = m0 + 64 * wy + 16 * mt + ln15;
      float4 o;
      o.x = acc[mt][nt][0] + b4.x;
      o.y = acc[mt][nt][1] + b4.y;
      o.z = acc[mt][nt][2] + b4.z;
      o.w = acc[mt][nt][3] + b4.w;
      *(float4*)(out + (size_t)n * D_MODEL + j0) = o;
    }
  }
}

extern "C" void kernel_launch(void* const* d_in, const int* in_sizes, int n_in,
                              void* d_out, int out_size, void* d_ws, size_t ws_size,
                              hipStream_t stream) {
  const float* x  = (const float*)d_in[0];
  const float* wq = (const float*)d_in[1];
  const float* bq = (const float*)d_in[2];
  const float* wk = (const float*)d_in[3];
  const float* bk = (const float*)d_in[4];
  const float* wv = (const float*)d_in[5];
  const float* bv = (const float*)d_in[6];
  const float* wo = (const float*)d_in[7];
  const float* bo = (const float*)d_in[8];
  float* out = (float*)d_out;

  // workspace layout (bf16 elements); xb..wob contiguous for cvt_all;
  // wq|wk|wv contiguous -> stacked [3072,1024] for merged qkv_gemm
  unsigned short* ws   = (unsigned short*)d_ws;
  unsigned short* xb   = ws;              // 8388608
  unsigned short* wall = ws + 8388608;    // [3072][1024] = wq|wk|wv
  unsigned short* wob  = ws + 11534336;
  unsigned short* Qb   = ws + 12582912;   // [B,H,S,Dh]
  unsigned short* Kb   = ws + 20971520;   // [B,H,S,Dh]
  unsigned short* Vtb  = ws + 29360128;   // [B,H,Dh,S]
  unsigned short* ctxb = ws + 37748736;   // [N, D]

  cvt_all<<<12288, 256, 0, stream>>>(x, wq, wk, wv, wo, ws);

  qkv_gemm<<<dim3(64, 24), 256, 0, stream>>>(xb, wall, bq, bk, bv, Qb, Kb, Vtb);
  attn_kernel<<<dim3(16, 64), 256, 0, stream>>>(Qb, Kb, Vtb, ctxb);
  oproj_kernel<<<dim3(64, 8), 256, 0, stream>>>(ctxb, wob, bo, out);
}